// Round 8
// baseline (1269.244 us; speedup 1.0000x reference)
//
#include <hip/hip_runtime.h>
#include <hip/hip_bf16.h>
#include <math.h>

#define B_SZ 2
#define LSEQ 2048
#define DM   1024
#define DI   2048
#define NTOK (B_SZ*LSEQ)
#define EPSV 1e-5f

typedef __attribute__((ext_vector_type(8))) short short8v;
typedef __attribute__((ext_vector_type(4))) short short4v;
typedef __attribute__((ext_vector_type(4))) float f4v;

static __device__ __forceinline__ float sigmoidf_(float v) {
    return 1.f / (1.f + __expf(-v));
}
static __device__ __forceinline__ float softplus_(float v) {
    return fmaxf(v, 0.f) + log1pf(__expf(-fabsf(v)));
}
static __device__ __forceinline__ short f2bf(float f) {
    __hip_bfloat16 h = __float2bfloat16(f);   // RNE
    return *reinterpret_cast<short*>(&h);
}
static __device__ __forceinline__ float bf2f(short s) {
    union { unsigned u; float f; } c;
    c.u = ((unsigned)(unsigned short)s) << 16;
    return c.f;
}

// ---------------- adaln modulation
__global__ __launch_bounds__(256) void mod_kernel(const float* __restrict__ c,
                                                  const float* __restrict__ w,
                                                  const float* __restrict__ bias,
                                                  float* __restrict__ mod) {
    int jt = blockIdx.x * 32;
    int jj = threadIdx.x & 31, ks = threadIdx.x >> 5;
    int j = jt + jj;
    const float* c0 = c;
    const float* c1 = c + 1024;
    float a0 = 0.f, a1 = 0.f;
    int k0 = ks * 128;
#pragma unroll 4
    for (int k = k0; k < k0 + 128; ++k) {
        float wv = w[(size_t)k * 3072 + j];
        a0 = fmaf(c0[k], wv, a0);
        a1 = fmaf(c1[k], wv, a1);
    }
    __shared__ float red[2][8][32];
    red[0][ks][jj] = a0;
    red[1][ks][jj] = a1;
    __syncthreads();
    if (threadIdx.x < 64) {
        int bb = threadIdx.x >> 5, j2 = threadIdx.x & 31;
        float s = bias[jt + j2];
#pragma unroll
        for (int kk = 0; kk < 8; ++kk) s += red[bb][kk][j2];
        mod[bb * 3072 + jt + j2] = s;
    }
}

// ---------------- layernorm + adaln scale/shift -> bf16
__global__ __launch_bounds__(256) void adaln_kernel(const float* __restrict__ x,
                                                    const float* __restrict__ mod,
                                                    __hip_bfloat16* __restrict__ h) {
    int row = blockIdx.x;
    int b = row >> 11;
    const float* xr = x + (size_t)row * DM;
    float v[4], s = 0.f, s2 = 0.f;
#pragma unroll
    for (int i = 0; i < 4; ++i) {
        v[i] = xr[threadIdx.x + i * 256];
        s += v[i]; s2 += v[i] * v[i];
    }
#pragma unroll
    for (int off = 32; off; off >>= 1) { s += __shfl_xor(s, off); s2 += __shfl_xor(s2, off); }
    __shared__ float red[8];
    int wid = threadIdx.x >> 6;
    if ((threadIdx.x & 63) == 0) { red[wid] = s; red[4 + wid] = s2; }
    __syncthreads();
    s  = red[0] + red[1] + red[2] + red[3];
    s2 = red[4] + red[5] + red[6] + red[7];
    float mu  = s * (1.f / DM);
    float var = s2 * (1.f / DM) - mu * mu;
    float rstd = rsqrtf(var + EPSV);
    const float* mb = mod + b * 3072;
    __hip_bfloat16* hr = h + (size_t)row * DM;
#pragma unroll
    for (int i = 0; i < 4; ++i) {
        int d = threadIdx.x + i * 256;
        hr[d] = __float2bfloat16((v[i] - mu) * rstd * (1.f + mb[1024 + d]) + mb[d]);
    }
}

// ---------------- bf16 MFMA GEMM (R5 structure: register-prefetch staging)
template <int ACCUM>
__global__ __launch_bounds__(256) void gemm_bf16_kernel(
    const short* __restrict__ A, int lda,
    const short* __restrict__ Bt, int ldb,
    float* __restrict__ C, int ldc, int K)
{
    __shared__ short As[128][40];
    __shared__ short Bs[128][40];
    int tid = threadIdx.x;
    int m0 = blockIdx.y * 128, n0 = blockIdx.x * 128;
    int wave = tid >> 6, lane = tid & 63;
    int wm = (wave & 1) * 64, wn = (wave >> 1) * 64;
    int srow = tid >> 2, sq = (tid & 3) * 8;
    const short* aptr = A + (size_t)(m0 + srow) * lda + sq;
    const short* bptr = Bt + (size_t)(n0 + srow) * ldb + sq;
    int fr = lane & 15, fq = lane >> 4;
    f4v acc[4][4];
#pragma unroll
    for (int i = 0; i < 4; ++i)
#pragma unroll
        for (int j = 0; j < 4; ++j) acc[i][j] = (f4v){0.f, 0.f, 0.f, 0.f};

    short8v a0 = *(const short8v*)(aptr);
    short8v a1 = *(const short8v*)(aptr + 64 * (size_t)lda);
    short8v b0 = *(const short8v*)(bptr);
    short8v b1 = *(const short8v*)(bptr + 64 * (size_t)ldb);
    for (int k0 = 0; k0 < K; k0 += 32) {
        __syncthreads();
        *(short8v*)&As[srow][sq]      = a0;
        *(short8v*)&As[srow + 64][sq] = a1;
        *(short8v*)&Bs[srow][sq]      = b0;
        *(short8v*)&Bs[srow + 64][sq] = b1;
        __syncthreads();
        if (k0 + 32 < K) {
            a0 = *(const short8v*)(aptr + k0 + 32);
            a1 = *(const short8v*)(aptr + 64 * (size_t)lda + k0 + 32);
            b0 = *(const short8v*)(bptr + k0 + 32);
            b1 = *(const short8v*)(bptr + 64 * (size_t)ldb + k0 + 32);
        }
        short8v af[4], bf[4];
#pragma unroll
        for (int i = 0; i < 4; ++i) af[i] = *(const short8v*)&As[wm + i * 16 + fr][fq * 8];
#pragma unroll
        for (int j = 0; j < 4; ++j) bf[j] = *(const short8v*)&Bs[wn + j * 16 + fr][fq * 8];
#pragma unroll
        for (int i = 0; i < 4; ++i)
#pragma unroll
            for (int j = 0; j < 4; ++j)
                acc[i][j] = __builtin_amdgcn_mfma_f32_16x16x32_bf16(af[i], bf[j], acc[i][j], 0, 0, 0);
    }
#pragma unroll
    for (int i = 0; i < 4; ++i)
#pragma unroll
        for (int j = 0; j < 4; ++j) {
#pragma unroll
            for (int r = 0; r < 4; ++r) {
                int row = m0 + wm + i * 16 + fq * 4 + r;
                int col = n0 + wn + j * 16 + fr;
                float* cp = C + (size_t)row * ldc + col;
                if (ACCUM) *cp += acc[i][j][r]; else *cp = acc[i][j][r];
            }
        }
}

// ---------------- weight cast+transpose: w[K][N] fp32 -> wT[N][K] bf16
__global__ __launch_bounds__(256) void wcast_kernel(const float* __restrict__ w,
                                                    int K, int N,
                                                    short* __restrict__ wT) {
    __shared__ short tile[32][33];
    int c0 = blockIdx.x * 32, r0 = blockIdx.y * 32;
    int tx = threadIdx.x & 31, ty = threadIdx.x >> 5;
#pragma unroll
    for (int i = 0; i < 32; i += 8)
        tile[ty + i][tx] = f2bf(w[(size_t)(r0 + ty + i) * N + c0 + tx]);
    __syncthreads();
#pragma unroll
    for (int i = 0; i < 32; i += 8)
        wT[(size_t)(c0 + ty + i) * K + r0 + tx] = tile[tx][ty + i];
}

// ---------------- silu on xs half of xz (fp32 in place) + bf16 copy
__global__ void silu_xs_kernel(float* __restrict__ xz, __hip_bfloat16* __restrict__ xsb) {
    int idx = blockIdx.x * 256 + threadIdx.x;
    int row = idx >> 9, c = (idx & 511) << 2;
    float4* p = (float4*)(xz + (size_t)row * 4096 + c);
    float4 v = *p;
    v.x *= sigmoidf_(v.x); v.y *= sigmoidf_(v.y);
    v.z *= sigmoidf_(v.z); v.w *= sigmoidf_(v.w);
    *p = v;
    short4v s = {f2bf(v.x), f2bf(v.y), f2bf(v.z), f2bf(v.w)};
    *(short4v*)((short*)xsb + (size_t)row * 2048 + c) = s;
}

// ---------------- in-place transpose of square 4096x4096 fp32
__global__ __launch_bounds__(256) void transpose_inplace_kernel(float* __restrict__ M) {
    int bj = blockIdx.x, bi = blockIdx.y;
    if (bi > bj) return;
    __shared__ float ta[32][33], tb[32][33];
    int tx = threadIdx.x & 31, ty = threadIdx.x >> 5;
    size_t oA = ((size_t)bi * 32) * 4096 + (size_t)bj * 32;
    size_t oB = ((size_t)bj * 32) * 4096 + (size_t)bi * 32;
#pragma unroll
    for (int i = 0; i < 32; i += 8)
        ta[ty + i][tx] = M[oA + (size_t)(ty + i) * 4096 + tx];
    if (bi != bj) {
#pragma unroll
        for (int i = 0; i < 32; i += 8)
            tb[ty + i][tx] = M[oB + (size_t)(ty + i) * 4096 + tx];
    }
    __syncthreads();
#pragma unroll
    for (int i = 0; i < 32; i += 8)
        M[oB + (size_t)(ty + i) * 4096 + tx] = ta[tx][ty + i];
    if (bi != bj) {
#pragma unroll
        for (int i = 0; i < 32; i += 8)
            M[oA + (size_t)(ty + i) * 4096 + tx] = tb[tx][ty + i];
    }
}

// ---------------- dt: softplus(proj[:, :2048]+bias), transposed -> bf16 [2048][4096]
__global__ __launch_bounds__(256) void transpose_dt_kernel(const float* __restrict__ proj,
                                                           const float* __restrict__ bias,
                                                           short* __restrict__ dtT) {
    __shared__ short tile[32][33];
    int c0 = blockIdx.x * 32, r0 = blockIdx.y * 32;
    int tx = threadIdx.x & 31, ty = threadIdx.x >> 5;
#pragma unroll
    for (int i = 0; i < 32; i += 8) {
        float v = proj[(size_t)(r0 + ty + i) * 2176 + c0 + tx];
        tile[ty + i][tx] = f2bf(softplus_(v + bias[c0 + tx]));
    }
    __syncthreads();
#pragma unroll
    for (int i = 0; i < 32; i += 8)
        dtT[(size_t)(c0 + ty + i) * 4096 + r0 + tx] = tile[tx][ty + i];
}

// ---------------- bf16 transpose: in[2048][4096] -> out[4096][2048]
__global__ __launch_bounds__(256) void transpose_bf16_kernel(const short* __restrict__ in,
                                                             short* __restrict__ outp) {
    __shared__ short tile[32][33];
    int c0 = blockIdx.x * 32, r0 = blockIdx.y * 32;
    int tx = threadIdx.x & 31, ty = threadIdx.x >> 5;
#pragma unroll
    for (int i = 0; i < 32; i += 8)
        tile[ty + i][tx] = in[(size_t)(r0 + ty + i) * 4096 + c0 + tx];
    __syncthreads();
#pragma unroll
    for (int i = 0; i < 32; i += 8)
        outp[(size_t)(c0 + ty + i) * 2048 + r0 + tx] = tile[tx][ty + i];
}

// ---------------- selective scan, R8: R7 + full-chunk (32 t) register
// prefetch of the HBM-streamed dt/xs (issued one chunk ahead -> ~1500+
// SIMD-cycles of latency cover vs ~900-cyc HBM). B/C keep 8-t lookahead
// (L2-resident). Chunk regs consumed with compile-time REV-folded indices.
#define SLOADBC(ib, s0_) {                                               \
    int sc_ = (s0_) > (LSEQ - 8) ? (LSEQ - 8) : (s0_);                   \
    _Pragma("unroll")                                                    \
    for (int i_ = 0; i_ < 8; ++i_) {                                     \
        int sl_ = sc_ + i_;                                              \
        int tm_ = REV ? (LSEQ - 1) - sl_ : sl_;                          \
        const float* pr_ = projb + (size_t)tm_ * 2176;                   \
        Bbuf[ib][i_] = pr_[2048 + lane];                                 \
        Cbuf[ib][i_] = pr_[2112 + lane];                                 \
    } }

#define SCOMP8(kk, ib)                                                   \
    _Pragma("unroll")                                                    \
    for (int i_ = 0; i_ < 8; ++i_) {                                     \
        int u_ = (kk) * 8 + i_;                                          \
        int m_ = REV ? 31 - u_ : u_;                                     \
        float dtv_ = bf2f(dtc[m_ >> 3][m_ & 7]);                         \
        float xsv_ = xsc[m_ >> 2][m_ & 3];                               \
        float e_ = __builtin_amdgcn_exp2f(dtv_ * Ae);                    \
        hst = fmaf(hst, e_, (dtv_ * xsv_) * Bbuf[ib][i_]);               \
        Lw[u_ * 65] = hst * Cbuf[ib][i_];                                \
    }

template <int REV>
__global__ __launch_bounds__(256) void scan_kernel(
    const float* __restrict__ proj,          // [NTOK][2176], B/C at cols 2048..
    const __hip_bfloat16* __restrict__ dtTp, // [2048][4096] bf16, d-major
    const float* __restrict__ xzT,           // [4096][4096] fp32 d-major
    const float* __restrict__ A_log, const float* __restrict__ Dsk,
    __hip_bfloat16* __restrict__ yT)         // [2048][4096] bf16 d-major
{
    __shared__ float lds[4][32 * 65];
    int lane = threadIdx.x & 63;
    int wv4 = threadIdx.x >> 6;
    int wave = blockIdx.x * 4 + wv4;
    int b = __builtin_amdgcn_readfirstlane(wave >> 11);
    int d = __builtin_amdgcn_readfirstlane(wave & 2047);
    float A  = -__expf(A_log[d * 64 + lane]);
    float Ae = A * 1.44269504f;
    float Dv = Dsk[d];
    const float* projb = proj + (size_t)b * LSEQ * 2176;
    const short* sdt = (const short*)dtTp + (size_t)d * 4096 + b * 2048;
    const float* sxs = xzT + (size_t)d * 4096 + b * 2048;
    const float* szz = xzT + (size_t)(2048 + d) * 4096 + b * 2048;
    __hip_bfloat16* yrow = yT + (size_t)d * 4096 + b * 2048;
    float* Lw = &lds[wv4][0] + lane;
    const float* Lr = &lds[wv4][0] + (lane & 31) * 65 + (lane >> 5) * 32;
    float hst = 0.f;

    float Bbuf[2][8], Cbuf[2][8];
    short8v dtc[4], dtn[4];
    f4v xsc[8], xsn[8];

    // prologue: current chunk (s0=0) streams + first B/C block
    {
        int cb0 = REV ? (LSEQ - 32) : 0;
#pragma unroll
        for (int q = 0; q < 4; ++q) dtc[q] = *(const short8v*)(sdt + cb0 + 8 * q);
#pragma unroll
        for (int q = 0; q < 8; ++q) xsc[q] = *(const f4v*)(sxs + cb0 + 4 * q);
    }
    SLOADBC(0, 0);

    for (int s0 = 0; s0 < LSEQ; s0 += 32) {
        // full-chunk prefetch of next chunk's dt/xs streams
        int s0n = (s0 + 32 < LSEQ) ? s0 + 32 : s0;
        int cbn = REV ? (LSEQ - 32) - s0n : s0n;
#pragma unroll
        for (int q = 0; q < 4; ++q) dtn[q] = *(const short8v*)(sdt + cbn + 8 * q);
#pragma unroll
        for (int q = 0; q < 8; ++q) xsn[q] = *(const f4v*)(sxs + cbn + 4 * q);

        SLOADBC(1, s0 + 8);   SCOMP8(0, 0);
        SLOADBC(0, s0 + 16);  SCOMP8(1, 1);
        SLOADBC(1, s0 + 24);  SCOMP8(2, 0);
        SLOADBC(0, s0 + 32);  SCOMP8(3, 1);

        // epilogue: reduce 64 states for this chunk's 32 timesteps
        float ssum = 0.f;
#pragma unroll
        for (int k = 0; k < 32; ++k) ssum += Lr[k];
        ssum += __shfl_xor(ssum, 32);
        if (lane < 32) {
            int tm = REV ? (LSEQ - 1) - (s0 + lane) : (s0 + lane);
            float xv = sxs[tm];
            float zv = szz[tm];
            yrow[tm] = __float2bfloat16(fmaf(xv, Dv, ssum) * (zv * sigmoidf_(zv)));
        }
        // rotate chunk registers
#pragma unroll
        for (int q = 0; q < 4; ++q) dtc[q] = dtn[q];
#pragma unroll
        for (int q = 0; q < 8; ++q) xsc[q] = xsn[q];
    }
}

// ---------------- out = x + gate * v
__global__ void gated_add_kernel(const float* __restrict__ x, const float* __restrict__ v,
                                 const float* __restrict__ mod, float* __restrict__ out) {
    int idx = blockIdx.x * 256 + threadIdx.x;
    int row = idx >> 8, b = row >> 11, c = (idx & 255) << 2;
    size_t o = (size_t)row * 1024 + c;
    float4 xv = *(const float4*)(x + o);
    float4 hv = *(const float4*)(v + o);
    float4 gv = *(const float4*)(mod + b * 3072 + 2048 + c);
    float4 r = {fmaf(gv.x, hv.x, xv.x), fmaf(gv.y, hv.y, xv.y),
                fmaf(gv.z, hv.z, xv.z), fmaf(gv.w, hv.w, xv.w)};
    *(float4*)(out + o) = r;
}

// ---------------- g = silu(a) * b  -> bf16
__global__ void silumul_kernel(const float* __restrict__ a, const float* __restrict__ bb,
                               __hip_bfloat16* __restrict__ g) {
    int idx = blockIdx.x * 256 + threadIdx.x;
    size_t o = (size_t)idx << 2;
    float4 av = *(const float4*)(a + o);
    float4 bv = *(const float4*)(bb + o);
    short4v r = {f2bf(av.x * sigmoidf_(av.x) * bv.x), f2bf(av.y * sigmoidf_(av.y) * bv.y),
                 f2bf(av.z * sigmoidf_(av.z) * bv.z), f2bf(av.w * sigmoidf_(av.w) * bv.w)};
    *(short4v*)((short*)g + o) = r;
}

extern "C" void kernel_launch(void* const* d_in, const int* in_sizes, int n_in,
                              void* d_out, int out_size, void* d_ws, size_t ws_size,
                              hipStream_t stream) {
    const float* x         = (const float*)d_in[0];
    const float* c         = (const float*)d_in[1];
    const float* adw_mamba = (const float*)d_in[2];
    const float* adb_mamba = (const float*)d_in[3];
    const float* adw_mlp   = (const float*)d_in[4];
    const float* adb_mlp   = (const float*)d_in[5];
    const float* mlp_w1    = (const float*)d_in[6];
    const float* mlp_w2    = (const float*)d_in[7];
    const float* mlp_w3    = (const float*)d_in[8];
    const float* in_w[2]    = {(const float*)d_in[9],  (const float*)d_in[15]};
    const float* xproj_w[2] = {(const float*)d_in[10], (const float*)d_in[16]};
    const float* dt_bias[2] = {(const float*)d_in[11], (const float*)d_in[17]};
    const float* A_log[2]   = {(const float*)d_in[12], (const float*)d_in[18]};
    const float* Dsk[2]     = {(const float*)d_in[13], (const float*)d_in[19]};
    const float* out_w[2]   = {(const float*)d_in[14], (const float*)d_in[20]};
    float* out = (float*)d_out;

    // workspace (float units), ~54.3M floats = 217 MB  (R5 layout)
    float* ws    = (float*)d_ws;
    float* mod   = ws;                                  // 12288
    short* h_bf  = (short*)(ws + 12288);                // 4096x1024 bf16
    float* xz    = ws + 12288 + 2097152;                // 4096x4096 fp32
    float* proj  = xz + 16777216;                       // 4096x2176 fp32
    float* scr   = proj + 8912896;                      // xs_bf | dtT | ybtok (time-shared)
    short* xs_bf = (short*)scr;                         // 4096x2048 bf16
    short* dtT   = (short*)scr;                         // 2048x4096 bf16
    short* ybtok = (short*)scr;                         // 4096x2048 bf16
    short* yTb   = (short*)(scr + 4194304);             // 2048x4096 bf16 (scan out; later g)
    float* hsum  = scr + 8388608;                       // 4096x1024 fp32
    short* wb    = (short*)(hsum + 4194304);            // bf16 weights
    short* inw_b[2]  = {wb,            wb + 4194304};
    short* xpj_b[2]  = {wb + 8388608,  wb + 12845056};
    short* outw_b[2] = {wb + 17301504, wb + 19398656};
    short* w1_b = wb + 21495808;
    short* w2_b = wb + 23592960;
    short* w3_b = wb + 25690112;

    dim3 blk(256);

    for (int dir = 0; dir < 2; ++dir) {
        wcast_kernel<<<dim3(128, 32), blk, 0, stream>>>(in_w[dir],   1024, 4096, inw_b[dir]);
        wcast_kernel<<<dim3(68, 64),  blk, 0, stream>>>(xproj_w[dir],2048, 2176, xpj_b[dir]);
        wcast_kernel<<<dim3(32, 64),  blk, 0, stream>>>(out_w[dir],  2048, 1024, outw_b[dir]);
    }
    wcast_kernel<<<dim3(64, 32), blk, 0, stream>>>(mlp_w1, 1024, 2048, w1_b);
    wcast_kernel<<<dim3(64, 32), blk, 0, stream>>>(mlp_w2, 1024, 2048, w2_b);
    wcast_kernel<<<dim3(32, 64), blk, 0, stream>>>(mlp_w3, 2048, 1024, w3_b);

    mod_kernel<<<96, blk, 0, stream>>>(c, adw_mamba, adb_mamba, mod);
    mod_kernel<<<96, blk, 0, stream>>>(c, adw_mlp,   adb_mlp,   mod + 6144);
    adaln_kernel<<<NTOK, blk, 0, stream>>>(x, mod, (__hip_bfloat16*)h_bf);

    for (int dir = 0; dir < 2; ++dir) {
        // xz = h @ in_w   (M=4096,N=4096,K=1024)
        gemm_bf16_kernel<0><<<dim3(32, 32), blk, 0, stream>>>(h_bf, 1024, inw_b[dir], 1024, xz, 4096, 1024);
        silu_xs_kernel<<<8192, blk, 0, stream>>>(xz, (__hip_bfloat16*)xs_bf);
        // proj = xs @ xproj_w  (M=4096,N=2176,K=2048)
        gemm_bf16_kernel<0><<<dim3(17, 32), blk, 0, stream>>>(xs_bf, 2048, xpj_b[dir], 2048, proj, 2176, 2048);
        transpose_inplace_kernel<<<dim3(128, 128), blk, 0, stream>>>(xz);
        transpose_dt_kernel<<<dim3(64, 128), blk, 0, stream>>>(proj, dt_bias[dir], dtT);
        if (dir == 0)
            scan_kernel<0><<<1024, blk, 0, stream>>>(proj, (const __hip_bfloat16*)dtT, xz,
                                                     A_log[dir], Dsk[dir], (__hip_bfloat16*)yTb);
        else
            scan_kernel<1><<<1024, blk, 0, stream>>>(proj, (const __hip_bfloat16*)dtT, xz,
                                                     A_log[dir], Dsk[dir], (__hip_bfloat16*)yTb);
        transpose_bf16_kernel<<<dim3(128, 64), blk, 0, stream>>>(yTb, ybtok);
        // hsum (+)= y @ out_w  (M=4096,N=1024,K=2048)
        if (dir == 0)
            gemm_bf16_kernel<0><<<dim3(8, 32), blk, 0, stream>>>(ybtok, 2048, outw_b[dir], 2048, hsum, 1024, 2048);
        else
            gemm_bf16_kernel<1><<<dim3(8, 32), blk, 0, stream>>>(ybtok, 2048, outw_b[dir], 2048, hsum, 1024, 2048);
    }

    gated_add_kernel<<<4096, blk, 0, stream>>>(x, hsum, mod, out);
    adaln_kernel<<<NTOK, blk, 0, stream>>>(out, mod + 6144, (__hip_bfloat16*)h_bf);
    gemm_bf16_kernel<0><<<dim3(16, 32), blk, 0, stream>>>(h_bf, 1024, w1_b, 1024, xz, 2048, 1024);
    gemm_bf16_kernel<0><<<dim3(16, 32), blk, 0, stream>>>(h_bf, 1024, w2_b, 1024, xz + (size_t)NTOK * 2048, 2048, 1024);
    silumul_kernel<<<8192, blk, 0, stream>>>(xz, xz + (size_t)NTOK * 2048, (__hip_bfloat16*)yTb);
    gemm_bf16_kernel<0><<<dim3(8, 32), blk, 0, stream>>>(yTb, 2048, w3_b, 2048, hsum, 1024, 2048);
    gated_add_kernel<<<4096, blk, 0, stream>>>(out, hsum, mod + 6144, out);
}

// Round 9
// 1228.050 us; speedup vs baseline: 1.0335x; 1.0335x over previous
//
#include <hip/hip_runtime.h>
#include <hip/hip_bf16.h>
#include <math.h>

#define B_SZ 2
#define LSEQ 2048
#define DM   1024
#define DI   2048
#define NTOK (B_SZ*LSEQ)
#define EPSV 1e-5f

typedef __attribute__((ext_vector_type(8))) short short8v;
typedef __attribute__((ext_vector_type(4))) short short4v;
typedef __attribute__((ext_vector_type(4))) float f4v;

static __device__ __forceinline__ float sigmoidf_(float v) {
    return 1.f / (1.f + __expf(-v));
}
static __device__ __forceinline__ float softplus_(float v) {
    return fmaxf(v, 0.f) + log1pf(__expf(-fabsf(v)));
}
static __device__ __forceinline__ short f2bf(float f) {
    __hip_bfloat16 h = __float2bfloat16(f);   // RNE
    return *reinterpret_cast<short*>(&h);
}
static __device__ __forceinline__ float bf2f(short s) {
    union { unsigned u; float f; } c;
    c.u = ((unsigned)(unsigned short)s) << 16;
    return c.f;
}

// ---------------- adaln modulation
__global__ __launch_bounds__(256) void mod_kernel(const float* __restrict__ c,
                                                  const float* __restrict__ w,
                                                  const float* __restrict__ bias,
                                                  float* __restrict__ mod) {
    int jt = blockIdx.x * 32;
    int jj = threadIdx.x & 31, ks = threadIdx.x >> 5;
    int j = jt + jj;
    const float* c0 = c;
    const float* c1 = c + 1024;
    float a0 = 0.f, a1 = 0.f;
    int k0 = ks * 128;
#pragma unroll 4
    for (int k = k0; k < k0 + 128; ++k) {
        float wv = w[(size_t)k * 3072 + j];
        a0 = fmaf(c0[k], wv, a0);
        a1 = fmaf(c1[k], wv, a1);
    }
    __shared__ float red[2][8][32];
    red[0][ks][jj] = a0;
    red[1][ks][jj] = a1;
    __syncthreads();
    if (threadIdx.x < 64) {
        int bb = threadIdx.x >> 5, j2 = threadIdx.x & 31;
        float s = bias[jt + j2];
#pragma unroll
        for (int kk = 0; kk < 8; ++kk) s += red[bb][kk][j2];
        mod[bb * 3072 + jt + j2] = s;
    }
}

// ---------------- layernorm + adaln scale/shift -> bf16 (first adaln)
__global__ __launch_bounds__(256) void adaln_kernel(const float* __restrict__ x,
                                                    const float* __restrict__ mod,
                                                    __hip_bfloat16* __restrict__ h) {
    int row = blockIdx.x;
    int b = row >> 11;
    const float* xr = x + (size_t)row * DM;
    float v[4], s = 0.f, s2 = 0.f;
#pragma unroll
    for (int i = 0; i < 4; ++i) {
        v[i] = xr[threadIdx.x + i * 256];
        s += v[i]; s2 += v[i] * v[i];
    }
#pragma unroll
    for (int off = 32; off; off >>= 1) { s += __shfl_xor(s, off); s2 += __shfl_xor(s2, off); }
    __shared__ float red[8];
    int wid = threadIdx.x >> 6;
    if ((threadIdx.x & 63) == 0) { red[wid] = s; red[4 + wid] = s2; }
    __syncthreads();
    s  = red[0] + red[1] + red[2] + red[3];
    s2 = red[4] + red[5] + red[6] + red[7];
    float mu  = s * (1.f / DM);
    float var = s2 * (1.f / DM) - mu * mu;
    float rstd = rsqrtf(var + EPSV);
    const float* mb = mod + b * 3072;
    __hip_bfloat16* hr = h + (size_t)row * DM;
#pragma unroll
    for (int i = 0; i < 4; ++i) {
        int d = threadIdx.x + i * 256;
        hr[d] = __float2bfloat16((v[i] - mu) * rstd * (1.f + mb[1024 + d]) + mb[d]);
    }
}

// ---------------- fused: out = x + gate*v, then layernorm+adaln -> bf16 h
__global__ __launch_bounds__(256) void gated_adaln_kernel(const float* __restrict__ x,
                                                          const float* __restrict__ v,
                                                          const float* __restrict__ modg,
                                                          const float* __restrict__ modln,
                                                          float* __restrict__ out,
                                                          __hip_bfloat16* __restrict__ h) {
    int row = blockIdx.x;
    int b = row >> 11;
    size_t o0 = (size_t)row * DM;
    float val[4], s = 0.f, s2 = 0.f;
    const float* gb = modg + b * 3072 + 2048;
#pragma unroll
    for (int i = 0; i < 4; ++i) {
        int d = threadIdx.x + i * 256;
        val[i] = fmaf(gb[d], v[o0 + d], x[o0 + d]);
        out[o0 + d] = val[i];
        s += val[i]; s2 += val[i] * val[i];
    }
#pragma unroll
    for (int off = 32; off; off >>= 1) { s += __shfl_xor(s, off); s2 += __shfl_xor(s2, off); }
    __shared__ float red[8];
    int wid = threadIdx.x >> 6;
    if ((threadIdx.x & 63) == 0) { red[wid] = s; red[4 + wid] = s2; }
    __syncthreads();
    s  = red[0] + red[1] + red[2] + red[3];
    s2 = red[4] + red[5] + red[6] + red[7];
    float mu  = s * (1.f / DM);
    float var = s2 * (1.f / DM) - mu * mu;
    float rstd = rsqrtf(var + EPSV);
    const float* mb = modln + b * 3072;
    __hip_bfloat16* hr = h + o0;
#pragma unroll
    for (int i = 0; i < 4; ++i) {
        int d = threadIdx.x + i * 256;
        hr[d] = __float2bfloat16((val[i] - mu) * rstd * (1.f + mb[1024 + d]) + mb[d]);
    }
}

// ---------------- bf16 MFMA GEMM (R5 structure: register-prefetch staging)
template <int ACCUM>
__global__ __launch_bounds__(256) void gemm_bf16_kernel(
    const short* __restrict__ A, int lda,
    const short* __restrict__ Bt, int ldb,
    float* __restrict__ C, int ldc, int K)
{
    __shared__ short As[128][40];
    __shared__ short Bs[128][40];
    int tid = threadIdx.x;
    int m0 = blockIdx.y * 128, n0 = blockIdx.x * 128;
    int wave = tid >> 6, lane = tid & 63;
    int wm = (wave & 1) * 64, wn = (wave >> 1) * 64;
    int srow = tid >> 2, sq = (tid & 3) * 8;
    const short* aptr = A + (size_t)(m0 + srow) * lda + sq;
    const short* bptr = Bt + (size_t)(n0 + srow) * ldb + sq;
    int fr = lane & 15, fq = lane >> 4;
    f4v acc[4][4];
#pragma unroll
    for (int i = 0; i < 4; ++i)
#pragma unroll
        for (int j = 0; j < 4; ++j) acc[i][j] = (f4v){0.f, 0.f, 0.f, 0.f};

    short8v a0 = *(const short8v*)(aptr);
    short8v a1 = *(const short8v*)(aptr + 64 * (size_t)lda);
    short8v b0 = *(const short8v*)(bptr);
    short8v b1 = *(const short8v*)(bptr + 64 * (size_t)ldb);
    for (int k0 = 0; k0 < K; k0 += 32) {
        __syncthreads();
        *(short8v*)&As[srow][sq]      = a0;
        *(short8v*)&As[srow + 64][sq] = a1;
        *(short8v*)&Bs[srow][sq]      = b0;
        *(short8v*)&Bs[srow + 64][sq] = b1;
        __syncthreads();
        if (k0 + 32 < K) {
            a0 = *(const short8v*)(aptr + k0 + 32);
            a1 = *(const short8v*)(aptr + 64 * (size_t)lda + k0 + 32);
            b0 = *(const short8v*)(bptr + k0 + 32);
            b1 = *(const short8v*)(bptr + 64 * (size_t)ldb + k0 + 32);
        }
        short8v af[4], bf[4];
#pragma unroll
        for (int i = 0; i < 4; ++i) af[i] = *(const short8v*)&As[wm + i * 16 + fr][fq * 8];
#pragma unroll
        for (int j = 0; j < 4; ++j) bf[j] = *(const short8v*)&Bs[wn + j * 16 + fr][fq * 8];
#pragma unroll
        for (int i = 0; i < 4; ++i)
#pragma unroll
            for (int j = 0; j < 4; ++j)
                acc[i][j] = __builtin_amdgcn_mfma_f32_16x16x32_bf16(af[i], bf[j], acc[i][j], 0, 0, 0);
    }
#pragma unroll
    for (int i = 0; i < 4; ++i)
#pragma unroll
        for (int j = 0; j < 4; ++j) {
#pragma unroll
            for (int r = 0; r < 4; ++r) {
                int row = m0 + wm + i * 16 + fq * 4 + r;
                int col = n0 + wn + j * 16 + fr;
                float* cp = C + (size_t)row * ldc + col;
                if (ACCUM) *cp += acc[i][j][r]; else *cp = acc[i][j][r];
            }
        }
}

// ---------------- weight cast+transpose: w[K][N] fp32 -> wT[N][K] bf16
__global__ __launch_bounds__(256) void wcast_kernel(const float* __restrict__ w,
                                                    int K, int N,
                                                    short* __restrict__ wT) {
    __shared__ short tile[32][33];
    int c0 = blockIdx.x * 32, r0 = blockIdx.y * 32;
    int tx = threadIdx.x & 31, ty = threadIdx.x >> 5;
#pragma unroll
    for (int i = 0; i < 32; i += 8)
        tile[ty + i][tx] = f2bf(w[(size_t)(r0 + ty + i) * N + c0 + tx]);
    __syncthreads();
#pragma unroll
    for (int i = 0; i < 32; i += 8)
        wT[(size_t)(c0 + ty + i) * K + r0 + tx] = tile[tx][ty + i];
}

// ---------------- fused silu + in-place transpose of xz (4096x4096 fp32).
// Reads xz token-major, applies silu to the xs half (cols<2048) on load,
// writes bf16 silu'd xs token-major (for proj GEMM), writes transposed fp32
// back in place (for the scan). Replaces silu_xs + transpose_inplace:
// 351 MB -> 150 MB of traffic per direction.
__global__ __launch_bounds__(256) void silu_transpose_kernel(float* __restrict__ M,
                                                             short* __restrict__ xsb) {
    int bj = blockIdx.x, bi = blockIdx.y;
    if (bi > bj) return;
    __shared__ float ta[32][33], tb[32][33];
    int tx = threadIdx.x & 31, ty = threadIdx.x >> 5;
    size_t oA = ((size_t)bi * 32) * 4096 + (size_t)bj * 32;
    size_t oB = ((size_t)bj * 32) * 4096 + (size_t)bi * 32;
    bool xsA = (bj < 64);   // tile A cols (bj*32+tx) < 2048
    bool xsB = (bi < 64);   // tile B cols (bi*32+tx) < 2048
#pragma unroll
    for (int i = 0; i < 32; i += 8) {
        float v = M[oA + (size_t)(ty + i) * 4096 + tx];
        if (xsA) {
            v *= sigmoidf_(v);
            xsb[(size_t)(bi * 32 + ty + i) * 2048 + bj * 32 + tx] = f2bf(v);
        }
        ta[ty + i][tx] = v;
    }
    if (bi != bj) {
#pragma unroll
        for (int i = 0; i < 32; i += 8) {
            float v = M[oB + (size_t)(ty + i) * 4096 + tx];
            if (xsB) {
                v *= sigmoidf_(v);
                xsb[(size_t)(bj * 32 + ty + i) * 2048 + bi * 32 + tx] = f2bf(v);
            }
            tb[ty + i][tx] = v;
        }
    }
    __syncthreads();
#pragma unroll
    for (int i = 0; i < 32; i += 8)
        M[oB + (size_t)(ty + i) * 4096 + tx] = ta[tx][ty + i];
    if (bi != bj) {
#pragma unroll
        for (int i = 0; i < 32; i += 8)
            M[oA + (size_t)(ty + i) * 4096 + tx] = tb[tx][ty + i];
    }
}

// ---------------- dt: softplus(proj[:, :2048]+bias), transposed -> bf16 [2048][4096]
__global__ __launch_bounds__(256) void transpose_dt_kernel(const float* __restrict__ proj,
                                                           const float* __restrict__ bias,
                                                           short* __restrict__ dtT) {
    __shared__ short tile[32][33];
    int c0 = blockIdx.x * 32, r0 = blockIdx.y * 32;
    int tx = threadIdx.x & 31, ty = threadIdx.x >> 5;
#pragma unroll
    for (int i = 0; i < 32; i += 8) {
        float v = proj[(size_t)(r0 + ty + i) * 2176 + c0 + tx];
        tile[ty + i][tx] = f2bf(softplus_(v + bias[c0 + tx]));
    }
    __syncthreads();
#pragma unroll
    for (int i = 0; i < 32; i += 8)
        dtT[(size_t)(c0 + ty + i) * 4096 + r0 + tx] = tile[tx][ty + i];
}

// ---------------- bf16 transpose: in[2048][4096] -> out[4096][2048]
__global__ __launch_bounds__(256) void transpose_bf16_kernel(const short* __restrict__ in,
                                                             short* __restrict__ outp) {
    __shared__ short tile[32][33];
    int c0 = blockIdx.x * 32, r0 = blockIdx.y * 32;
    int tx = threadIdx.x & 31, ty = threadIdx.x >> 5;
#pragma unroll
    for (int i = 0; i < 32; i += 8)
        tile[ty + i][tx] = in[(size_t)(r0 + ty + i) * 4096 + c0 + tx];
    __syncthreads();
#pragma unroll
    for (int i = 0; i < 32; i += 8)
        outp[(size_t)(c0 + ty + i) * 2048 + r0 + tx] = tile[tx][ty + i];
}

// ---------------- selective scan (exact R7 structure — measured best 238 us)
#define SLOAD(ib, s0_) {                                                 \
    int sc_ = (s0_) > (LSEQ - 8) ? (LSEQ - 8) : (s0_);                   \
    int bs_ = REV ? (LSEQ - 8) - sc_ : sc_;                              \
    short8v dtv_ = *(const short8v*)(sdt + bs_);                         \
    float4 xv0_ = *(const float4*)(sxs + bs_);                           \
    float4 xv1_ = *(const float4*)(sxs + bs_ + 4);                       \
    _Pragma("unroll")                                                    \
    for (int i_ = 0; i_ < 8; ++i_) {                                     \
        int j_ = REV ? 7 - i_ : i_;                                      \
        dts[ib][i_] = bf2f(dtv_[j_]);                                    \
        xss[ib][i_] = j_ < 4 ? ((const float*)&xv0_)[j_]                 \
                             : ((const float*)&xv1_)[j_ - 4];            \
        int sl_ = sc_ + i_;                                              \
        int tm_ = REV ? (LSEQ - 1) - sl_ : sl_;                          \
        const float* pr_ = projb + (size_t)tm_ * 2176;                   \
        Bbuf[ib][i_] = pr_[2048 + lane];                                 \
        Cbuf[ib][i_] = pr_[2112 + lane];                                 \
    } }

#define SCOMP(ib, r0_)                                                   \
    _Pragma("unroll")                                                    \
    for (int i_ = 0; i_ < 8; ++i_) {                                     \
        float e_ = __builtin_amdgcn_exp2f(dts[ib][i_] * Ae);             \
        float u_ = dts[ib][i_] * xss[ib][i_];                            \
        hst = fmaf(hst, e_, u_ * Bbuf[ib][i_]);                          \
        Lw[((r0_) + i_) * 65] = hst * Cbuf[ib][i_];                      \
    }

template <int REV>
__global__ __launch_bounds__(256) void scan_kernel(
    const float* __restrict__ proj,          // [NTOK][2176], B/C at cols 2048..
    const __hip_bfloat16* __restrict__ dtTp, // [2048][4096] bf16, d-major
    const float* __restrict__ xzT,           // [4096][4096] fp32 d-major
    const float* __restrict__ A_log, const float* __restrict__ Dsk,
    __hip_bfloat16* __restrict__ yT)         // [2048][4096] bf16 d-major
{
    __shared__ float lds[4][32 * 65];
    int lane = threadIdx.x & 63;
    int wv4 = threadIdx.x >> 6;
    int wave = blockIdx.x * 4 + wv4;
    int b = __builtin_amdgcn_readfirstlane(wave >> 11);
    int d = __builtin_amdgcn_readfirstlane(wave & 2047);
    float A  = -__expf(A_log[d * 64 + lane]);
    float Ae = A * 1.44269504f;
    float Dv = Dsk[d];
    const float* projb = proj + (size_t)b * LSEQ * 2176;
    const short* sdt = (const short*)dtTp + (size_t)d * 4096 + b * 2048;
    const float* sxs = xzT + (size_t)d * 4096 + b * 2048;
    const float* szz = xzT + (size_t)(2048 + d) * 4096 + b * 2048;
    __hip_bfloat16* yrow = yT + (size_t)d * 4096 + b * 2048;
    float* Lw = &lds[wv4][0] + lane;
    const float* Lr = &lds[wv4][0] + (lane & 31) * 65 + (lane >> 5) * 32;
    float hst = 0.f;

    float dts[2][8], xss[2][8], Bbuf[2][8], Cbuf[2][8];
    SLOAD(0, 0);
    for (int s0 = 0; s0 < LSEQ; s0 += 32) {
        SLOAD(1, s0 + 8);  SCOMP(0, 0);
        SLOAD(0, s0 + 16); SCOMP(1, 8);
        SLOAD(1, s0 + 24); SCOMP(0, 16);
        SLOAD(0, s0 + 32); SCOMP(1, 24);
        float ssum = 0.f;
#pragma unroll
        for (int k = 0; k < 32; ++k) ssum += Lr[k];
        ssum += __shfl_xor(ssum, 32);
        if (lane < 32) {
            int tm = REV ? (LSEQ - 1) - (s0 + lane) : (s0 + lane);
            float xv = sxs[tm];
            float zv = szz[tm];
            yrow[tm] = __float2bfloat16(fmaf(xv, Dv, ssum) * (zv * sigmoidf_(zv)));
        }
    }
}

// ---------------- out = x + gate * v (final residual)
__global__ void gated_add_kernel(const float* __restrict__ x, const float* __restrict__ v,
                                 const float* __restrict__ mod, float* __restrict__ out) {
    int idx = blockIdx.x * 256 + threadIdx.x;
    int row = idx >> 8, b = row >> 11, c = (idx & 255) << 2;
    size_t o = (size_t)row * 1024 + c;
    float4 xv = *(const float4*)(x + o);
    float4 hv = *(const float4*)(v + o);
    float4 gv = *(const float4*)(mod + b * 3072 + 2048 + c);
    float4 r = {fmaf(gv.x, hv.x, xv.x), fmaf(gv.y, hv.y, xv.y),
                fmaf(gv.z, hv.z, xv.z), fmaf(gv.w, hv.w, xv.w)};
    *(float4*)(out + o) = r;
}

// ---------------- g = silu(a) * b -> bf16 ; a,b interleaved in one [tok][4096] buffer
__global__ void silumul_kernel(const float* __restrict__ ab, __hip_bfloat16* __restrict__ g) {
    int idx = blockIdx.x * 256 + threadIdx.x;
    int row = idx >> 9, c = (idx & 511) << 2;
    size_t o = (size_t)row * 4096 + c;
    float4 av = *(const float4*)(ab + o);
    float4 bv = *(const float4*)(ab + o + 2048);
    short4v r = {f2bf(av.x * sigmoidf_(av.x) * bv.x), f2bf(av.y * sigmoidf_(av.y) * bv.y),
                 f2bf(av.z * sigmoidf_(av.z) * bv.z), f2bf(av.w * sigmoidf_(av.w) * bv.w)};
    *(short4v*)((short*)g + (size_t)row * 2048 + c) = r;
}

extern "C" void kernel_launch(void* const* d_in, const int* in_sizes, int n_in,
                              void* d_out, int out_size, void* d_ws, size_t ws_size,
                              hipStream_t stream) {
    const float* x         = (const float*)d_in[0];
    const float* c         = (const float*)d_in[1];
    const float* adw_mamba = (const float*)d_in[2];
    const float* adb_mamba = (const float*)d_in[3];
    const float* adw_mlp   = (const float*)d_in[4];
    const float* adb_mlp   = (const float*)d_in[5];
    const float* mlp_w1    = (const float*)d_in[6];
    const float* mlp_w2    = (const float*)d_in[7];
    const float* mlp_w3    = (const float*)d_in[8];
    const float* in_w[2]    = {(const float*)d_in[9],  (const float*)d_in[15]};
    const float* xproj_w[2] = {(const float*)d_in[10], (const float*)d_in[16]};
    const float* dt_bias[2] = {(const float*)d_in[11], (const float*)d_in[17]};
    const float* A_log[2]   = {(const float*)d_in[12], (const float*)d_in[18]};
    const float* Dsk[2]     = {(const float*)d_in[13], (const float*)d_in[19]};
    const float* out_w[2]   = {(const float*)d_in[14], (const float*)d_in[20]};
    float* out = (float*)d_out;

    // workspace (float units), ~54.3M floats = 217 MB  (R5/R7 layout)
    float* ws    = (float*)d_ws;
    float* mod   = ws;                                  // 12288
    short* h_bf  = (short*)(ws + 12288);                // 4096x1024 bf16
    float* xz    = ws + 12288 + 2097152;                // 4096x4096 fp32
    float* proj  = xz + 16777216;                       // 4096x2176 fp32
    float* scr   = proj + 8912896;                      // xs_bf | dtT | ybtok (time-shared)
    short* xs_bf = (short*)scr;                         // 4096x2048 bf16
    short* dtT   = (short*)scr;                         // 2048x4096 bf16
    short* ybtok = (short*)scr;                         // 4096x2048 bf16
    short* yTb   = (short*)(scr + 4194304);             // 2048x4096 bf16 (scan out; later g)
    float* hsum  = scr + 8388608;                       // 4096x1024 fp32
    short* wb    = (short*)(hsum + 4194304);            // bf16 weights
    short* inw_b[2]  = {wb,            wb + 4194304};
    short* xpj_b[2]  = {wb + 8388608,  wb + 12845056};
    short* outw_b[2] = {wb + 17301504, wb + 19398656};
    short* w12_b = wb + 21495808;                       // [4096][1024] = w1|w2 concat
    short* w3_b  = wb + 25690112;

    dim3 blk(256);

    for (int dir = 0; dir < 2; ++dir) {
        wcast_kernel<<<dim3(128, 32), blk, 0, stream>>>(in_w[dir],   1024, 4096, inw_b[dir]);
        wcast_kernel<<<dim3(68, 64),  blk, 0, stream>>>(xproj_w[dir],2048, 2176, xpj_b[dir]);
        wcast_kernel<<<dim3(32, 64),  blk, 0, stream>>>(out_w[dir],  2048, 1024, outw_b[dir]);
    }
    wcast_kernel<<<dim3(64, 32), blk, 0, stream>>>(mlp_w1, 1024, 2048, w12_b);
    wcast_kernel<<<dim3(64, 32), blk, 0, stream>>>(mlp_w2, 1024, 2048, w12_b + 2097152);
    wcast_kernel<<<dim3(32, 64), blk, 0, stream>>>(mlp_w3, 2048, 1024, w3_b);

    mod_kernel<<<96, blk, 0, stream>>>(c, adw_mamba, adb_mamba, mod);
    mod_kernel<<<96, blk, 0, stream>>>(c, adw_mlp,   adb_mlp,   mod + 6144);
    adaln_kernel<<<NTOK, blk, 0, stream>>>(x, mod, (__hip_bfloat16*)h_bf);

    for (int dir = 0; dir < 2; ++dir) {
        // xz = h @ in_w   (M=4096,N=4096,K=1024), token-major fp32
        gemm_bf16_kernel<0><<<dim3(32, 32), blk, 0, stream>>>(h_bf, 1024, inw_b[dir], 1024, xz, 4096, 1024);
        // fused: silu(xs) + bf16 copy + in-place transpose to d-major
        silu_transpose_kernel<<<dim3(128, 128), blk, 0, stream>>>(xz, xs_bf);
        // proj = xs @ xproj_w  (M=4096,N=2176,K=2048)
        gemm_bf16_kernel<0><<<dim3(17, 32), blk, 0, stream>>>(xs_bf, 2048, xpj_b[dir], 2048, proj, 2176, 2048);
        transpose_dt_kernel<<<dim3(64, 128), blk, 0, stream>>>(proj, dt_bias[dir], dtT);
        if (dir == 0)
            scan_kernel<0><<<1024, blk, 0, stream>>>(proj, (const __hip_bfloat16*)dtT, xz,
                                                     A_log[dir], Dsk[dir], (__hip_bfloat16*)yTb);
        else
            scan_kernel<1><<<1024, blk, 0, stream>>>(proj, (const __hip_bfloat16*)dtT, xz,
                                                     A_log[dir], Dsk[dir], (__hip_bfloat16*)yTb);
        transpose_bf16_kernel<<<dim3(128, 64), blk, 0, stream>>>(yTb, ybtok);
        // hsum (+)= y @ out_w  (M=4096,N=1024,K=2048)
        if (dir == 0)
            gemm_bf16_kernel<0><<<dim3(8, 32), blk, 0, stream>>>(ybtok, 2048, outw_b[dir], 2048, hsum, 1024, 2048);
        else
            gemm_bf16_kernel<1><<<dim3(8, 32), blk, 0, stream>>>(ybtok, 2048, outw_b[dir], 2048, hsum, 1024, 2048);
    }

    // fused: out = x + gate_mamba*hsum, then adaln_mlp -> h_bf
    gated_adaln_kernel<<<NTOK, blk, 0, stream>>>(x, hsum, mod, mod + 6144, out, (__hip_bfloat16*)h_bf);
    // merged mlp w1|w2: [tok][4096] with a in cols 0..2047, b in 2048..4095
    gemm_bf16_kernel<0><<<dim3(32, 32), blk, 0, stream>>>(h_bf, 1024, w12_b, 1024, xz, 4096, 1024);
    silumul_kernel<<<8192, blk, 0, stream>>>(xz, (__hip_bfloat16*)yTb);
    // mlp_out = g @ w3  (M=4096,N=1024,K=2048)
    gemm_bf16_kernel<0><<<dim3(8, 32), blk, 0, stream>>>(yTb, 2048, w3_b, 2048, hsum, 1024, 2048);
    gated_add_kernel<<<4096, blk, 0, stream>>>(out, hsum, mod + 6144, out);
}